// Round 4
// baseline (375.825 us; speedup 1.0000x reference)
//
#include <hip/hip_runtime.h>
#include <hip/hip_bf16.h>
#include <cstdint>
#include <cstddef>

#define NI 8192
#define NC 8192
#define RV 7
#define DD 256

typedef __bf16  bf16x8 __attribute__((ext_vector_type(8)));
typedef float   f32x4  __attribute__((ext_vector_type(4)));
typedef __fp16  f16x2  __attribute__((ext_vector_type(2)));

// ws layout:
//   imgs: per img-block ib (32) x chunk t=r*8+j (56): [4 u][256 row] x 16B = 16KB
//   caps: per cap-block cb (32) x k-chunk j (8):      [4 u][256 row] x 16B = 16KB
#define IMGS_WS_BYTES (32u * 56u * 16384u)   /* 29,360,128 */
#define CAPS_WS_OFF   IMGS_WS_BYTES
#define CAPS_WS_BYTES (32u * 8u * 16384u)    /* 4,194,304 */
#define WS_NEEDED     ((size_t)(IMGS_WS_BYTES + CAPS_WS_BYTES))

static __device__ __forceinline__ unsigned pkbf(float x, float y) {
  unsigned a = __float_as_uint(x) + 0x8000u;
  unsigned b = __float_as_uint(y) + 0x8000u;
  return __builtin_amdgcn_perm(b, a, 0x07060302u);
}

static __device__ __forceinline__ void gload16(const void* g, void* l) {
  __builtin_amdgcn_global_load_lds(
      (const __attribute__((address_space(1))) void*)g,
      (__attribute__((address_space(3))) void*)l, 16, 0, 0);
}

// ---------------- conversion pre-passes (f32 -> bf16, tile-image layout) ---
__global__ __launch_bounds__(256)
void conv_imgs(const float* __restrict__ imgs, uint4* __restrict__ ws) {
  unsigned T = blockIdx.x * 256u + threadIdx.x;   // 0..1,835,007
  unsigned img = T / 224u;                        // 8192 imgs x 224 units
  unsigned rem = T - img * 224u;
  unsigned r  = rem >> 5;                         // view 0..6
  unsigned ju = rem & 31u;                        // k-unit 0..31 (k = ju*8)
  const float* s = imgs + ((size_t)img * RV + r) * DD + ju * 8u;
  float4 a = *(const float4*)s;
  float4 b = *(const float4*)(s + 4);
  uint4 v = { pkbf(a.x, a.y), pkbf(a.z, a.w), pkbf(b.x, b.y), pkbf(b.z, b.w) };
  unsigned ib = img >> 8, lrow = img & 255u;
  unsigned j = ju >> 2, u = ju & 3u;
  unsigned t = r * 8u + j;
  unsigned byteoff = (ib * 56u + t) * 16384u + u * 4096u + lrow * 16u;
  ws[byteoff >> 4] = v;
}

__global__ __launch_bounds__(256)
void conv_caps(const float* __restrict__ caps, uint4* __restrict__ ws) {
  unsigned T = blockIdx.x * 256u + threadIdx.x;   // 0..262,143
  unsigned gr = T >> 5;                           // cap row 0..8191
  unsigned ju = T & 31u;                          // k-unit 0..31
  const float* s = caps + (size_t)gr * DD + ju * 8u;
  float4 a = *(const float4*)s;
  float4 b = *(const float4*)(s + 4);
  uint4 v = { pkbf(a.x, a.y), pkbf(a.z, a.w), pkbf(b.x, b.y), pkbf(b.z, b.w) };
  unsigned cb = gr >> 8, row = gr & 255u;
  unsigned j = ju >> 2, u = ju & 3u;
  unsigned byteoff = cb * 131072u + j * 16384u + u * 4096u + row * 16u;
  ws[byteoff >> 4] = v;
}

// ---------------- main GEMM+max kernel ------------------------------------
// block tile 256 imgs x 256 caps; 8 waves (2m x 4n), wave tile 128x64.
// BK=32 chunks, A and B both chunk-staged, 4-deep (4x16KB each = 128KB LDS).
// One sync point per chunk: counted vmcnt(8) + s_barrier per 32 MFMA/wave.
// omax kept packed f16x2 (64 VGPR) to fit acc(128)+operands in 256 VGPR.
__global__ __launch_bounds__(512, 2)
void mvm_mfma(const char* __restrict__ wi, const char* __restrict__ wcap,
              float* __restrict__ out)
{
  __shared__ __align__(1024) char lds[131072];
  char* const ldsA = lds;            // 4 x 16KB imgs chunks
  char* const ldsB = lds + 65536;    // 4 x 16KB caps chunks

  const int tid  = threadIdx.x;
  const int lane = tid & 63;
  const int wid  = tid >> 6;
  const int wm   = wid >> 2;   // 0..1 : m-strip of 128
  const int wn   = wid & 3;    // 0..3 : n-strip of 64

  const int bid = (int)blockIdx.x;                 // 1024 blocks
  const int swz = (bid & 7) * 128 + (bid >> 3);    // bijective XCD swizzle
  const int ib  = swz >> 5;    // 0..31
  const int cb  = swz & 31;    // 0..31

  const char* abase = wi   + (size_t)ib * (56u * 16384u);
  const char* bbase = wcap + (size_t)cb * (8u * 16384u);

  // prologue: stage chunks 0..2 (A+B), 12 calls/wave outstanding
  #pragma unroll
  for (int c = 0; c < 3; ++c) {
    gload16(abase + c * 16384 + tid * 16,        ldsA + c * 16384 + wid * 1024);
    gload16(abase + c * 16384 + 8192 + tid * 16, ldsA + c * 16384 + 8192 + wid * 1024);
    gload16(bbase + c * 16384 + tid * 16,        ldsB + c * 16384 + wid * 1024);
    gload16(bbase + c * 16384 + 8192 + tid * 16, ldsB + c * 16384 + 8192 + wid * 1024);
  }
  asm volatile("s_waitcnt vmcnt(8)" ::: "memory");   // chunk 0 landed
  __builtin_amdgcn_s_barrier();
  asm volatile("" ::: "memory");

  const int lrow = lane & 15;
  const int lu   = lane >> 4;
  const char* const aB = ldsA + lu * 4096 + (wm * 128 + lrow) * 16;
  const char* const bB = ldsB + lu * 4096 + (wn * 64  + lrow) * 16;
  const char* ap = abase + 3 * 16384 + tid * 16;

  f16x2 om[8][4][2];
  #pragma unroll
  for (int m = 0; m < 8; ++m)
    #pragma unroll
    for (int n = 0; n < 4; ++n)
      #pragma unroll
      for (int h = 0; h < 2; ++h)
        om[m][n][h] = (f16x2){(__fp16)-65504.f, (__fp16)-65504.f};

  f32x4 acc[8][4];

  for (int r = 0; r < RV; ++r) {
    #pragma unroll
    for (int m = 0; m < 8; ++m)
      #pragma unroll
      for (int n = 0; n < 4; ++n)
        acc[m][n] = (f32x4){0.f, 0.f, 0.f, 0.f};

    #pragma unroll
    for (int j = 0; j < 8; ++j) {
      const int p = j & 3;         // buffer holding chunk t=r*8+j  (r*8 % 4 == 0)
      const int q = (j + 3) & 3;   // buffer receiving chunk t+3

      // stage chunk t+3 (A linear in t; B chunk index (j+3)&7; t+3>55 writes
      // land in a never-again-read buffer, source stays in-bounds of ws)
      gload16(ap,        ldsA + q * 16384 + wid * 1024);
      gload16(ap + 8192, ldsA + q * 16384 + 8192 + wid * 1024);
      gload16(bbase + ((j + 3) & 7) * 16384 + tid * 16,
              ldsB + q * 16384 + wid * 1024);
      gload16(bbase + ((j + 3) & 7) * 16384 + 8192 + tid * 16,
              ldsB + q * 16384 + 8192 + wid * 1024);
      ap += 16384;

      // fragment reads: B first, then A m0-3, then A m4-7 (in-order LDS
      // completion lets cluster1 start with the a4-7 reads still in flight)
      bf16x8 b0 = *(const bf16x8*)(bB + p * 16384 + 0 * 256);
      bf16x8 b1 = *(const bf16x8*)(bB + p * 16384 + 1 * 256);
      bf16x8 b2 = *(const bf16x8*)(bB + p * 16384 + 2 * 256);
      bf16x8 b3 = *(const bf16x8*)(bB + p * 16384 + 3 * 256);
      bf16x8 a0 = *(const bf16x8*)(aB + p * 16384 + 0 * 256);
      bf16x8 a1 = *(const bf16x8*)(aB + p * 16384 + 1 * 256);
      bf16x8 a2 = *(const bf16x8*)(aB + p * 16384 + 2 * 256);
      bf16x8 a3 = *(const bf16x8*)(aB + p * 16384 + 3 * 256);
      bf16x8 a4 = *(const bf16x8*)(aB + p * 16384 + 4 * 256);
      bf16x8 a5 = *(const bf16x8*)(aB + p * 16384 + 5 * 256);
      bf16x8 a6 = *(const bf16x8*)(aB + p * 16384 + 6 * 256);
      bf16x8 a7 = *(const bf16x8*)(aB + p * 16384 + 7 * 256);

      __builtin_amdgcn_s_setprio(1);
      acc[0][0] = __builtin_amdgcn_mfma_f32_16x16x32_bf16(a0, b0, acc[0][0], 0, 0, 0);
      acc[1][0] = __builtin_amdgcn_mfma_f32_16x16x32_bf16(a1, b0, acc[1][0], 0, 0, 0);
      acc[2][0] = __builtin_amdgcn_mfma_f32_16x16x32_bf16(a2, b0, acc[2][0], 0, 0, 0);
      acc[3][0] = __builtin_amdgcn_mfma_f32_16x16x32_bf16(a3, b0, acc[3][0], 0, 0, 0);
      acc[0][1] = __builtin_amdgcn_mfma_f32_16x16x32_bf16(a0, b1, acc[0][1], 0, 0, 0);
      acc[1][1] = __builtin_amdgcn_mfma_f32_16x16x32_bf16(a1, b1, acc[1][1], 0, 0, 0);
      acc[2][1] = __builtin_amdgcn_mfma_f32_16x16x32_bf16(a2, b1, acc[2][1], 0, 0, 0);
      acc[3][1] = __builtin_amdgcn_mfma_f32_16x16x32_bf16(a3, b1, acc[3][1], 0, 0, 0);
      acc[0][2] = __builtin_amdgcn_mfma_f32_16x16x32_bf16(a0, b2, acc[0][2], 0, 0, 0);
      acc[1][2] = __builtin_amdgcn_mfma_f32_16x16x32_bf16(a1, b2, acc[1][2], 0, 0, 0);
      acc[2][2] = __builtin_amdgcn_mfma_f32_16x16x32_bf16(a2, b2, acc[2][2], 0, 0, 0);
      acc[3][2] = __builtin_amdgcn_mfma_f32_16x16x32_bf16(a3, b2, acc[3][2], 0, 0, 0);
      acc[0][3] = __builtin_amdgcn_mfma_f32_16x16x32_bf16(a0, b3, acc[0][3], 0, 0, 0);
      acc[1][3] = __builtin_amdgcn_mfma_f32_16x16x32_bf16(a1, b3, acc[1][3], 0, 0, 0);
      acc[2][3] = __builtin_amdgcn_mfma_f32_16x16x32_bf16(a2, b3, acc[2][3], 0, 0, 0);
      acc[3][3] = __builtin_amdgcn_mfma_f32_16x16x32_bf16(a3, b3, acc[3][3], 0, 0, 0);
      __builtin_amdgcn_s_setprio(0);

      __builtin_amdgcn_s_setprio(1);
      acc[4][0] = __builtin_amdgcn_mfma_f32_16x16x32_bf16(a4, b0, acc[4][0], 0, 0, 0);
      acc[5][0] = __builtin_amdgcn_mfma_f32_16x16x32_bf16(a5, b0, acc[5][0], 0, 0, 0);
      acc[6][0] = __builtin_amdgcn_mfma_f32_16x16x32_bf16(a6, b0, acc[6][0], 0, 0, 0);
      acc[7][0] = __builtin_amdgcn_mfma_f32_16x16x32_bf16(a7, b0, acc[7][0], 0, 0, 0);
      acc[4][1] = __builtin_amdgcn_mfma_f32_16x16x32_bf16(a4, b1, acc[4][1], 0, 0, 0);
      acc[5][1] = __builtin_amdgcn_mfma_f32_16x16x32_bf16(a5, b1, acc[5][1], 0, 0, 0);
      acc[6][1] = __builtin_amdgcn_mfma_f32_16x16x32_bf16(a6, b1, acc[6][1], 0, 0, 0);
      acc[7][1] = __builtin_amdgcn_mfma_f32_16x16x32_bf16(a7, b1, acc[7][1], 0, 0, 0);
      acc[4][2] = __builtin_amdgcn_mfma_f32_16x16x32_bf16(a4, b2, acc[4][2], 0, 0, 0);
      acc[5][2] = __builtin_amdgcn_mfma_f32_16x16x32_bf16(a5, b2, acc[5][2], 0, 0, 0);
      acc[6][2] = __builtin_amdgcn_mfma_f32_16x16x32_bf16(a6, b2, acc[6][2], 0, 0, 0);
      acc[7][2] = __builtin_amdgcn_mfma_f32_16x16x32_bf16(a7, b2, acc[7][2], 0, 0, 0);
      acc[4][3] = __builtin_amdgcn_mfma_f32_16x16x32_bf16(a4, b3, acc[4][3], 0, 0, 0);
      acc[5][3] = __builtin_amdgcn_mfma_f32_16x16x32_bf16(a5, b3, acc[5][3], 0, 0, 0);
      acc[6][3] = __builtin_amdgcn_mfma_f32_16x16x32_bf16(a6, b3, acc[6][3], 0, 0, 0);
      acc[7][3] = __builtin_amdgcn_mfma_f32_16x16x32_bf16(a7, b3, acc[7][3], 0, 0, 0);
      __builtin_amdgcn_s_setprio(0);

      asm volatile("s_waitcnt vmcnt(8)" ::: "memory");  // chunk t+1 landed
      __builtin_amdgcn_s_barrier();
      asm volatile("" ::: "memory");
    }

    // fold view into running max (packed f16)
    #pragma unroll
    for (int m = 0; m < 8; ++m)
      #pragma unroll
      for (int n = 0; n < 4; ++n) {
        f16x2 lo = __builtin_amdgcn_cvt_pkrtz(acc[m][n][0], acc[m][n][1]);
        f16x2 hi = __builtin_amdgcn_cvt_pkrtz(acc[m][n][2], acc[m][n][3]);
        om[m][n][0] = __builtin_elementwise_max(om[m][n][0], lo);
        om[m][n][1] = __builtin_elementwise_max(om[m][n][1], hi);
      }
  }

  // epilogue: unpack f16 -> f32 and store
  const int rbase = ib * 256 + wm * 128;
  const int cbase = cb * 256 + wn * 64;
  #pragma unroll
  for (int m = 0; m < 8; ++m)
    #pragma unroll
    for (int h = 0; h < 2; ++h)
      #pragma unroll
      for (int e = 0; e < 2; ++e) {
        size_t ro = (size_t)(rbase + m * 16 + lu * 4 + h * 2 + e) * NC + cbase + lrow;
        #pragma unroll
        for (int n = 0; n < 4; ++n)
          out[ro + n * 16] = (float)om[m][n][h][e];
      }
}

// ---------------- fallback (no-ws path) ------------------------------------
__global__ __launch_bounds__(512, 1)
void mvm_fallback(const float* __restrict__ imgs, const float* __restrict__ caps,
                  float* __restrict__ out)
{
  __shared__ __align__(16) char ldsB[128 * 512];
  __shared__ __align__(16) char ldsA[2][256 * 128];

  const int tid  = threadIdx.x;
  const int lane = tid & 63;
  const int wid  = tid >> 6;
  const int wr   = wid >> 1;
  const int wc   = wid & 1;
  const int i0   = blockIdx.y * 256;
  const int c0   = blockIdx.x * 128;

  #pragma unroll
  for (int it = 0; it < 8; ++it) {
    int c    = tid + it * 512;
    int row  = c >> 5;
    int colb = (c & 31) * 16;
    const float* p = caps + (size_t)(c0 + row) * DD + (c & 31) * 8;
    float4 a = *(const float4*)p;
    float4 b = *(const float4*)(p + 4);
    uint4 v;
    v.x = pkbf(a.x, a.y); v.y = pkbf(a.z, a.w);
    v.z = pkbf(b.x, b.y); v.w = pkbf(b.z, b.w);
    *(uint4*)(ldsB + row * 512 + (colb ^ ((row & 7) << 4))) = v;
  }
  #pragma unroll
  for (int it = 0; it < 4; ++it) {
    int c    = tid + it * 512;
    int row  = c >> 3;
    int colb = (c & 7) * 16;
    const float* p = imgs + ((size_t)(i0 + row) * RV + 0) * DD + (c & 7) * 8;
    float4 a = *(const float4*)p;
    float4 b = *(const float4*)(p + 4);
    uint4 v;
    v.x = pkbf(a.x, a.y); v.y = pkbf(a.z, a.w);
    v.z = pkbf(b.x, b.y); v.w = pkbf(b.z, b.w);
    *(uint4*)(ldsA[0] + row * 128 + (colb ^ ((row & 7) << 4))) = v;
  }
  __syncthreads();

  f32x4 omax[4][4];
  #pragma unroll
  for (int m = 0; m < 4; ++m)
    #pragma unroll
    for (int n = 0; n < 4; ++n)
      #pragma unroll
      for (int j = 0; j < 4; ++j)
        omax[m][n][j] = -3.4e38f;

  f32x4 acc[4][4];
  int cur = 0;
  const int lrow = lane & 15;
  const int lkb  = (lane >> 4) * 16;

  for (int ch = 0; ch < RV * 4; ++ch) {
    const int kc = ch & 3;
    if (kc == 0) {
      #pragma unroll
      for (int m = 0; m < 4; ++m)
        #pragma unroll
        for (int n = 0; n < 4; ++n)
          acc[m][n] = (f32x4){0.f, 0.f, 0.f, 0.f};
    }
    const int  chn  = ch + 1;
    const bool hasn = (chn < RV * 4);
    float4 pf[8];
    if (hasn) {
      const int rn = chn >> 2;
      const int kn = (chn & 3) * 64;
      #pragma unroll
      for (int it = 0; it < 4; ++it) {
        int c   = tid + it * 512;
        int row = c >> 3;
        const float* p = imgs + ((size_t)(i0 + row) * RV + rn) * DD + kn + (c & 7) * 8;
        pf[2 * it]     = *(const float4*)p;
        pf[2 * it + 1] = *(const float4*)(p + 4);
      }
    }
    #pragma unroll
    for (int ks = 0; ks < 2; ++ks) {
      bf16x8 af[4], bfr[4];
      #pragma unroll
      for (int m = 0; m < 4; ++m) {
        int row = wr * 64 + m * 16 + lrow;
        af[m] = *(const bf16x8*)(ldsA[cur] + row * 128 + ((ks * 64 + lkb) ^ ((row & 7) << 4)));
      }
      #pragma unroll
      for (int n = 0; n < 4; ++n) {
        int row = wc * 64 + n * 16 + lrow;
        bfr[n] = *(const bf16x8*)(ldsB + row * 512 + (((ch & 3) * 128 + ks * 64 + lkb) ^ ((row & 7) << 4)));
      }
      #pragma unroll
      for (int m = 0; m < 4; ++m)
        #pragma unroll
        for (int n = 0; n < 4; ++n)
          acc[m][n] = __builtin_amdgcn_mfma_f32_16x16x32_bf16(af[m], bfr[n], acc[m][n], 0, 0, 0);
    }
    if (hasn) {
      #pragma unroll
      for (int it = 0; it < 4; ++it) {
        int c    = tid + it * 512;
        int row  = c >> 3;
        int colb = (c & 7) * 16;
        uint4 v;
        v.x = pkbf(pf[2 * it].x,     pf[2 * it].y);
        v.y = pkbf(pf[2 * it].z,     pf[2 * it].w);
        v.z = pkbf(pf[2 * it + 1].x, pf[2 * it + 1].y);
        v.w = pkbf(pf[2 * it + 1].z, pf[2 * it + 1].w);
        *(uint4*)(ldsA[cur ^ 1] + row * 128 + (colb ^ ((row & 7) << 4))) = v;
      }
    }
    __syncthreads();
    cur ^= 1;
    if (kc == 3) {
      #pragma unroll
      for (int m = 0; m < 4; ++m)
        #pragma unroll
        for (int n = 0; n < 4; ++n)
          #pragma unroll
          for (int j = 0; j < 4; ++j)
            omax[m][n][j] = fmaxf(omax[m][n][j], acc[m][n][j]);
    }
  }

  const int rbase = i0 + wr * 64;
  const int cbase = c0 + wc * 64;
  const int lr4   = (lane >> 4) * 4;
  const int lc    = lane & 15;
  #pragma unroll
  for (int m = 0; m < 4; ++m)
    #pragma unroll
    for (int j = 0; j < 4; ++j) {
      size_t ro = (size_t)(rbase + m * 16 + lr4 + j) * NC;
      #pragma unroll
      for (int n = 0; n < 4; ++n)
        out[ro + cbase + n * 16 + lc] = omax[m][n][j];
    }
}

extern "C" void kernel_launch(void* const* d_in, const int* in_sizes, int n_in,
                              void* d_out, int out_size, void* d_ws, size_t ws_size,
                              hipStream_t stream) {
  const float* imgs = (const float*)d_in[0];
  const float* caps = (const float*)d_in[1];
  float* out = (float*)d_out;

  if (ws_size >= WS_NEEDED) {
    char* ws = (char*)d_ws;
    conv_imgs<<<7168, 256, 0, stream>>>(imgs, (uint4*)ws);
    conv_caps<<<1024, 256, 0, stream>>>(caps, (uint4*)(ws + CAPS_WS_OFF));
    mvm_mfma<<<1024, 512, 0, stream>>>((const char*)ws, (const char*)(ws + CAPS_WS_OFF), out);
  } else {
    dim3 grid(NC / 128, NI / 256);
    mvm_fallback<<<grid, 512, 0, stream>>>(imgs, caps, out);
  }
}

// Round 5
// 258.801 us; speedup vs baseline: 1.4522x; 1.4522x over previous
//
#include <hip/hip_runtime.h>
#include <hip/hip_bf16.h>
#include <cstdint>
#include <cstddef>

#define NI 8192
#define NC 8192
#define RV 7
#define DD 256

typedef __bf16  bf16x8 __attribute__((ext_vector_type(8)));
typedef float   f32x4  __attribute__((ext_vector_type(4)));
typedef __fp16  f16x2  __attribute__((ext_vector_type(2)));

// ws layout:
//   imgs: per img-block ib (16) x chunk t=r*8+j (56): [4 u][512 row] x 16B = 32KB
//   caps: per cap-block cb (64): 8 chunks x [4 u][128 row] x 16B = 64KB
#define IMGS_WS_BYTES (16u * 56u * 32768u)   /* 29,360,128 */
#define CAPS_WS_OFF   IMGS_WS_BYTES
#define CAPS_WS_BYTES (64u * 65536u)         /* 4,194,304 */
#define WS_NEEDED     ((size_t)(IMGS_WS_BYTES + CAPS_WS_BYTES))

static __device__ __forceinline__ unsigned pkbf(float x, float y) {
  unsigned a = __float_as_uint(x) + 0x8000u;
  unsigned b = __float_as_uint(y) + 0x8000u;
  return __builtin_amdgcn_perm(b, a, 0x07060302u);
}

static __device__ __forceinline__ void gload16(const void* g, void* l) {
  __builtin_amdgcn_global_load_lds(
      (const __attribute__((address_space(1))) void*)g,
      (__attribute__((address_space(3))) void*)l, 16, 0, 0);
}

// ---------------- conversion pre-passes (f32 -> bf16, tile-image layout) ---
__global__ __launch_bounds__(256)
void conv_imgs(const float* __restrict__ imgs, uint4* __restrict__ ws) {
  unsigned T = blockIdx.x * 256u + threadIdx.x;   // 0..1,835,007
  unsigned img = T / 224u;                        // 8192 imgs x 224 units
  unsigned rem = T - img * 224u;
  unsigned r  = rem >> 5;                         // view 0..6
  unsigned ju = rem & 31u;                        // k-unit 0..31 (k = ju*8)
  const float* s = imgs + ((size_t)img * RV + r) * DD + ju * 8u;
  float4 a = *(const float4*)s;
  float4 b = *(const float4*)(s + 4);
  uint4 v = { pkbf(a.x, a.y), pkbf(a.z, a.w), pkbf(b.x, b.y), pkbf(b.z, b.w) };
  unsigned ib = img >> 9, lrow = img & 511u;
  unsigned j = ju >> 2, u = ju & 3u;
  unsigned t = r * 8u + j;
  unsigned byteoff = (ib * 56u + t) * 32768u + u * 8192u + lrow * 16u;
  ws[byteoff >> 4] = v;
}

__global__ __launch_bounds__(256)
void conv_caps(const float* __restrict__ caps, uint4* __restrict__ ws) {
  unsigned T = blockIdx.x * 256u + threadIdx.x;   // 0..262,143
  unsigned gr = T >> 5;                           // cap row 0..8191
  unsigned ju = T & 31u;                          // k-unit 0..31
  const float* s = caps + (size_t)gr * DD + ju * 8u;
  float4 a = *(const float4*)s;
  float4 b = *(const float4*)(s + 4);
  uint4 v = { pkbf(a.x, a.y), pkbf(a.z, a.w), pkbf(b.x, b.y), pkbf(b.z, b.w) };
  unsigned cb = gr >> 7, row = gr & 127u;
  unsigned j = ju >> 2, u = ju & 3u;
  unsigned byteoff = cb * 65536u + j * 8192u + u * 2048u + row * 16u;
  ws[byteoff >> 4] = v;
}

// ---------------- main GEMM+max kernel ------------------------------------
// block tile 512 imgs x 128 caps; 8 waves (4m x 2n), wave tile 128x64.
// B resident in LDS (64KB, staged once). A chunks BK=32 (32KB), dbuf x2.
// One barrier + one vmcnt(0) per phase of 32 MFMA/wave.
__global__ __launch_bounds__(512, 2)
void mvm_mfma(const char* __restrict__ wi, const char* __restrict__ wcap,
              float* __restrict__ out)
{
  __shared__ __align__(1024) char lds[131072];
  char* const ldsA = lds;            // 2 x 32KB imgs chunks
  char* const ldsB = lds + 65536;    // 64KB caps (full K, 8 sub-chunks)

  const int tid  = threadIdx.x;
  const int lane = tid & 63;
  const int wid  = tid >> 6;
  const int wm   = wid >> 1;   // 0..3 : m-strip of 128
  const int wn   = wid & 1;    // 0..1 : n-strip of 64

  const int bid = (int)blockIdx.x;                 // 1024 blocks
  const int swz = (bid & 7) * 128 + (bid >> 3);    // bijective XCD swizzle
  const int ib  = swz >> 6;    // 0..15 (same for all 32 same-XCD-resident blocks)
  const int cb  = swz & 63;    // 0..63

  const char* abase = wi   + (size_t)ib * (56u * 32768u);
  const char* bbase = wcap + (size_t)cb * 65536u;

  // prologue: stage all of B (8 gloads) + A chunk 0 (4 gloads)
  #pragma unroll
  for (int l = 0; l < 8; ++l)
    gload16(bbase + l * 8192 + tid * 16, ldsB + l * 8192 + wid * 1024);
  #pragma unroll
  for (int l = 0; l < 4; ++l)
    gload16(abase + l * 8192 + tid * 16, ldsA + l * 8192 + wid * 1024);

  asm volatile("s_waitcnt vmcnt(0)" ::: "memory");
  __builtin_amdgcn_s_barrier();
  asm volatile("" ::: "memory");

  const int lrow = lane & 15;
  const int lu   = lane >> 4;
  const char* const aB = ldsA + lu * 8192 + (wm * 128 + lrow) * 16;
  const char* const bB = ldsB + lu * 2048 + (wn * 64  + lrow) * 16;
  const char* ap = abase + 32768 + tid * 16;   // next chunk to stage = 1

  f16x2 om[8][4][2];
  #pragma unroll
  for (int m = 0; m < 8; ++m)
    #pragma unroll
    for (int n = 0; n < 4; ++n)
      #pragma unroll
      for (int h = 0; h < 2; ++h)
        om[m][n][h] = (f16x2){(__fp16)-65504.f, (__fp16)-65504.f};

  f32x4 acc[8][4];

  for (int r = 0; r < RV; ++r) {
    #pragma unroll
    for (int m = 0; m < 8; ++m)
      #pragma unroll
      for (int n = 0; n < 4; ++n)
        acc[m][n] = (f32x4){0.f, 0.f, 0.f, 0.f};

    #pragma unroll
    for (int j = 0; j < 8; ++j) {
      const int p = j & 1;             // buffer holding chunk t = r*8+j
      const bool more = (r < RV - 1) || (j < 7);

      // stage chunk t+1 into the other buffer (read in phase t-1, now free)
      if (more) {
        gload16(ap,         ldsA + (p ^ 1) * 32768 + 0 * 8192 + wid * 1024);
        gload16(ap +  8192, ldsA + (p ^ 1) * 32768 + 1 * 8192 + wid * 1024);
        gload16(ap + 16384, ldsA + (p ^ 1) * 32768 + 2 * 8192 + wid * 1024);
        gload16(ap + 24576, ldsA + (p ^ 1) * 32768 + 3 * 8192 + wid * 1024);
        ap += 32768;
      }

      // fragment reads: 4 B + 8 A (bank-conflict-free unit-major layout)
      bf16x8 b0 = *(const bf16x8*)(bB + j * 8192 + 0 * 256);
      bf16x8 b1 = *(const bf16x8*)(bB + j * 8192 + 1 * 256);
      bf16x8 b2 = *(const bf16x8*)(bB + j * 8192 + 2 * 256);
      bf16x8 b3 = *(const bf16x8*)(bB + j * 8192 + 3 * 256);
      bf16x8 a0 = *(const bf16x8*)(aB + p * 32768 + 0 * 256);
      bf16x8 a1 = *(const bf16x8*)(aB + p * 32768 + 1 * 256);
      bf16x8 a2 = *(const bf16x8*)(aB + p * 32768 + 2 * 256);
      bf16x8 a3 = *(const bf16x8*)(aB + p * 32768 + 3 * 256);
      bf16x8 a4 = *(const bf16x8*)(aB + p * 32768 + 4 * 256);
      bf16x8 a5 = *(const bf16x8*)(aB + p * 32768 + 5 * 256);
      bf16x8 a6 = *(const bf16x8*)(aB + p * 32768 + 6 * 256);
      bf16x8 a7 = *(const bf16x8*)(aB + p * 32768 + 7 * 256);

      __builtin_amdgcn_s_setprio(1);
      acc[0][0] = __builtin_amdgcn_mfma_f32_16x16x32_bf16(a0, b0, acc[0][0], 0, 0, 0);
      acc[1][0] = __builtin_amdgcn_mfma_f32_16x16x32_bf16(a1, b0, acc[1][0], 0, 0, 0);
      acc[2][0] = __builtin_amdgcn_mfma_f32_16x16x32_bf16(a2, b0, acc[2][0], 0, 0, 0);
      acc[3][0] = __builtin_amdgcn_mfma_f32_16x16x32_bf16(a3, b0, acc[3][0], 0, 0, 0);
      acc[4][0] = __builtin_amdgcn_mfma_f32_16x16x32_bf16(a4, b0, acc[4][0], 0, 0, 0);
      acc[5][0] = __builtin_amdgcn_mfma_f32_16x16x32_bf16(a5, b0, acc[5][0], 0, 0, 0);
      acc[6][0] = __builtin_amdgcn_mfma_f32_16x16x32_bf16(a6, b0, acc[6][0], 0, 0, 0);
      acc[7][0] = __builtin_amdgcn_mfma_f32_16x16x32_bf16(a7, b0, acc[7][0], 0, 0, 0);
      acc[0][1] = __builtin_amdgcn_mfma_f32_16x16x32_bf16(a0, b1, acc[0][1], 0, 0, 0);
      acc[1][1] = __builtin_amdgcn_mfma_f32_16x16x32_bf16(a1, b1, acc[1][1], 0, 0, 0);
      acc[2][1] = __builtin_amdgcn_mfma_f32_16x16x32_bf16(a2, b1, acc[2][1], 0, 0, 0);
      acc[3][1] = __builtin_amdgcn_mfma_f32_16x16x32_bf16(a3, b1, acc[3][1], 0, 0, 0);
      acc[4][1] = __builtin_amdgcn_mfma_f32_16x16x32_bf16(a4, b1, acc[4][1], 0, 0, 0);
      acc[5][1] = __builtin_amdgcn_mfma_f32_16x16x32_bf16(a5, b1, acc[5][1], 0, 0, 0);
      acc[6][1] = __builtin_amdgcn_mfma_f32_16x16x32_bf16(a6, b1, acc[6][1], 0, 0, 0);
      acc[7][1] = __builtin_amdgcn_mfma_f32_16x16x32_bf16(a7, b1, acc[7][1], 0, 0, 0);
      acc[0][2] = __builtin_amdgcn_mfma_f32_16x16x32_bf16(a0, b2, acc[0][2], 0, 0, 0);
      acc[1][2] = __builtin_amdgcn_mfma_f32_16x16x32_bf16(a1, b2, acc[1][2], 0, 0, 0);
      acc[2][2] = __builtin_amdgcn_mfma_f32_16x16x32_bf16(a2, b2, acc[2][2], 0, 0, 0);
      acc[3][2] = __builtin_amdgcn_mfma_f32_16x16x32_bf16(a3, b2, acc[3][2], 0, 0, 0);
      acc[4][2] = __builtin_amdgcn_mfma_f32_16x16x32_bf16(a4, b2, acc[4][2], 0, 0, 0);
      acc[5][2] = __builtin_amdgcn_mfma_f32_16x16x32_bf16(a5, b2, acc[5][2], 0, 0, 0);
      acc[6][2] = __builtin_amdgcn_mfma_f32_16x16x32_bf16(a6, b2, acc[6][2], 0, 0, 0);
      acc[7][2] = __builtin_amdgcn_mfma_f32_16x16x32_bf16(a7, b2, acc[7][2], 0, 0, 0);
      acc[0][3] = __builtin_amdgcn_mfma_f32_16x16x32_bf16(a0, b3, acc[0][3], 0, 0, 0);
      acc[1][3] = __builtin_amdgcn_mfma_f32_16x16x32_bf16(a1, b3, acc[1][3], 0, 0, 0);
      acc[2][3] = __builtin_amdgcn_mfma_f32_16x16x32_bf16(a2, b3, acc[2][3], 0, 0, 0);
      acc[3][3] = __builtin_amdgcn_mfma_f32_16x16x32_bf16(a3, b3, acc[3][3], 0, 0, 0);
      acc[4][3] = __builtin_amdgcn_mfma_f32_16x16x32_bf16(a4, b3, acc[4][3], 0, 0, 0);
      acc[5][3] = __builtin_amdgcn_mfma_f32_16x16x32_bf16(a5, b3, acc[5][3], 0, 0, 0);
      acc[6][3] = __builtin_amdgcn_mfma_f32_16x16x32_bf16(a6, b3, acc[6][3], 0, 0, 0);
      acc[7][3] = __builtin_amdgcn_mfma_f32_16x16x32_bf16(a7, b3, acc[7][3], 0, 0, 0);
      __builtin_amdgcn_s_setprio(0);

      if (more) {
        asm volatile("s_waitcnt vmcnt(0)" ::: "memory");  // chunk t+1 landed
        __builtin_amdgcn_s_barrier();
        asm volatile("" ::: "memory");
      }
    }

    // fold view into running max (packed f16)
    #pragma unroll
    for (int m = 0; m < 8; ++m)
      #pragma unroll
      for (int n = 0; n < 4; ++n) {
        f16x2 lo = __builtin_amdgcn_cvt_pkrtz(acc[m][n][0], acc[m][n][1]);
        f16x2 hi = __builtin_amdgcn_cvt_pkrtz(acc[m][n][2], acc[m][n][3]);
        om[m][n][0] = __builtin_elementwise_max(om[m][n][0], lo);
        om[m][n][1] = __builtin_elementwise_max(om[m][n][1], hi);
      }
  }

  // epilogue: unpack f16 -> f32 and store
  const int rbase = ib * 512 + wm * 128;
  const int cbase = cb * 128 + wn * 64;
  #pragma unroll
  for (int m = 0; m < 8; ++m)
    #pragma unroll
    for (int h = 0; h < 2; ++h)
      #pragma unroll
      for (int e = 0; e < 2; ++e) {
        size_t ro = (size_t)(rbase + m * 16 + lu * 4 + h * 2 + e) * NC + cbase + lrow;
        #pragma unroll
        for (int n = 0; n < 4; ++n)
          out[ro + n * 16] = (float)om[m][n][h][e];
      }
}

// ---------------- fallback (no-ws path) ------------------------------------
__global__ __launch_bounds__(512, 1)
void mvm_fallback(const float* __restrict__ imgs, const float* __restrict__ caps,
                  float* __restrict__ out)
{
  __shared__ __align__(16) char ldsB[128 * 512];
  __shared__ __align__(16) char ldsA[2][256 * 128];

  const int tid  = threadIdx.x;
  const int lane = tid & 63;
  const int wid  = tid >> 6;
  const int wr   = wid >> 1;
  const int wc   = wid & 1;
  const int i0   = blockIdx.y * 256;
  const int c0   = blockIdx.x * 128;

  #pragma unroll
  for (int it = 0; it < 8; ++it) {
    int c    = tid + it * 512;
    int row  = c >> 5;
    int colb = (c & 31) * 16;
    const float* p = caps + (size_t)(c0 + row) * DD + (c & 31) * 8;
    float4 a = *(const float4*)p;
    float4 b = *(const float4*)(p + 4);
    uint4 v;
    v.x = pkbf(a.x, a.y); v.y = pkbf(a.z, a.w);
    v.z = pkbf(b.x, b.y); v.w = pkbf(b.z, b.w);
    *(uint4*)(ldsB + row * 512 + (colb ^ ((row & 7) << 4))) = v;
  }
  #pragma unroll
  for (int it = 0; it < 4; ++it) {
    int c    = tid + it * 512;
    int row  = c >> 3;
    int colb = (c & 7) * 16;
    const float* p = imgs + ((size_t)(i0 + row) * RV + 0) * DD + (c & 7) * 8;
    float4 a = *(const float4*)p;
    float4 b = *(const float4*)(p + 4);
    uint4 v;
    v.x = pkbf(a.x, a.y); v.y = pkbf(a.z, a.w);
    v.z = pkbf(b.x, b.y); v.w = pkbf(b.z, b.w);
    *(uint4*)(ldsA[0] + row * 128 + (colb ^ ((row & 7) << 4))) = v;
  }
  __syncthreads();

  f32x4 omax[4][4];
  #pragma unroll
  for (int m = 0; m < 4; ++m)
    #pragma unroll
    for (int n = 0; n < 4; ++n)
      #pragma unroll
      for (int j = 0; j < 4; ++j)
        omax[m][n][j] = -3.4e38f;

  f32x4 acc[4][4];
  int cur = 0;
  const int lrow = lane & 15;
  const int lkb  = (lane >> 4) * 16;

  for (int ch = 0; ch < RV * 4; ++ch) {
    const int kc = ch & 3;
    if (kc == 0) {
      #pragma unroll
      for (int m = 0; m < 4; ++m)
        #pragma unroll
        for (int n = 0; n < 4; ++n)
          acc[m][n] = (f32x4){0.f, 0.f, 0.f, 0.f};
    }
    const int  chn  = ch + 1;
    const bool hasn = (chn < RV * 4);
    float4 pf[8];
    if (hasn) {
      const int rn = chn >> 2;
      const int kn = (chn & 3) * 64;
      #pragma unroll
      for (int it = 0; it < 4; ++it) {
        int c   = tid + it * 512;
        int row = c >> 3;
        const float* p = imgs + ((size_t)(i0 + row) * RV + rn) * DD + kn + (c & 7) * 8;
        pf[2 * it]     = *(const float4*)p;
        pf[2 * it + 1] = *(const float4*)(p + 4);
      }
    }
    #pragma unroll
    for (int ks = 0; ks < 2; ++ks) {
      bf16x8 af[4], bfr[4];
      #pragma unroll
      for (int m = 0; m < 4; ++m) {
        int row = wr * 64 + m * 16 + lrow;
        af[m] = *(const bf16x8*)(ldsA[cur] + row * 128 + ((ks * 64 + lkb) ^ ((row & 7) << 4)));
      }
      #pragma unroll
      for (int n = 0; n < 4; ++n) {
        int row = wc * 64 + n * 16 + lrow;
        bfr[n] = *(const bf16x8*)(ldsB + row * 512 + (((ch & 3) * 128 + ks * 64 + lkb) ^ ((row & 7) << 4)));
      }
      #pragma unroll
      for (int m = 0; m < 4; ++m)
        #pragma unroll
        for (int n = 0; n < 4; ++n)
          acc[m][n] = __builtin_amdgcn_mfma_f32_16x16x32_bf16(af[m], bfr[n], acc[m][n], 0, 0, 0);
    }
    if (hasn) {
      #pragma unroll
      for (int it = 0; it < 4; ++it) {
        int c    = tid + it * 512;
        int row  = c >> 3;
        int colb = (c & 7) * 16;
        uint4 v;
        v.x = pkbf(pf[2 * it].x,     pf[2 * it].y);
        v.y = pkbf(pf[2 * it].z,     pf[2 * it].w);
        v.z = pkbf(pf[2 * it + 1].x, pf[2 * it + 1].y);
        v.w = pkbf(pf[2 * it + 1].z, pf[2 * it + 1].w);
        *(uint4*)(ldsA[cur ^ 1] + row * 128 + (colb ^ ((row & 7) << 4))) = v;
      }
    }
    __syncthreads();
    cur ^= 1;
    if (kc == 3) {
      #pragma unroll
      for (int m = 0; m < 4; ++m)
        #pragma unroll
        for (int n = 0; n < 4; ++n)
          #pragma unroll
          for (int j = 0; j < 4; ++j)
            omax[m][n][j] = fmaxf(omax[m][n][j], acc[m][n][j]);
    }
  }

  const int rbase = i0 + wr * 64;
  const int cbase = c0 + wc * 64;
  const int lr4   = (lane >> 4) * 4;
  const int lc    = lane & 15;
  #pragma unroll
  for (int m = 0; m < 4; ++m)
    #pragma unroll
    for (int j = 0; j < 4; ++j) {
      size_t ro = (size_t)(rbase + m * 16 + lr4 + j) * NC;
      #pragma unroll
      for (int n = 0; n < 4; ++n)
        out[ro + cbase + n * 16 + lc] = omax[m][n][j];
    }
}

extern "C" void kernel_launch(void* const* d_in, const int* in_sizes, int n_in,
                              void* d_out, int out_size, void* d_ws, size_t ws_size,
                              hipStream_t stream) {
  const float* imgs = (const float*)d_in[0];
  const float* caps = (const float*)d_in[1];
  float* out = (float*)d_out;

  if (ws_size >= WS_NEEDED) {
    char* ws = (char*)d_ws;
    conv_imgs<<<7168, 256, 0, stream>>>(imgs, (uint4*)ws);
    conv_caps<<<1024, 256, 0, stream>>>(caps, (uint4*)(ws + CAPS_WS_OFF));
    mvm_mfma<<<1024, 512, 0, stream>>>((const char*)ws, (const char*)(ws + CAPS_WS_OFF), out);
  } else {
    dim3 grid(NC / 128, NI / 256);
    mvm_fallback<<<grid, 512, 0, stream>>>(imgs, caps, out);
  }
}